// Round 4
// baseline (180.147 us; speedup 1.0000x reference)
//
#include <hip/hip_runtime.h>
#include <hip/hip_bf16.h>
#include <cstdint>
#include <cstddef>

// Problem constants (from reference)
#define F0v   2048
#define F1v   2304
#define F2v   2560
#define E1v   256
#define E2v   256
#define BROWS 8192
#define ODIM  1024
#define NNZv  262144
#define NBv   1024

typedef __bf16 bf16x8 __attribute__((ext_vector_type(8)));
typedef float floatx4 __attribute__((ext_vector_type(4)));

__device__ __forceinline__ unsigned short f2bf(float f) {
  unsigned int u = __float_as_uint(f);
  u += 0x7FFFu + ((u >> 16) & 1u);   // round-to-nearest-even
  return (unsigned short)(u >> 16);
}

__device__ __forceinline__ void async_ld16(const void* g, void* l) {
  __builtin_amdgcn_global_load_lds(
      (const __attribute__((address_space(1))) unsigned int*)g,
      (__attribute__((address_space(3))) unsigned int*)l, 16, 0, 0);
}

// ---------------------------------------------------------------------------
// Kernel 1 (fused): proven round-0 version. Blocks [0,8192) build h rows
// (LDS-staged row -> gathers are LDS-hits; one barrier); blocks [8192,9216)
// do the COO scatter-add. (Wave-per-row global-gather variant regressed:
// +24 MB HBM over-fetch — gathers must be LDS-served.)
// ---------------------------------------------------------------------------
__global__ __launch_bounds__(256) void fused_pre_kernel(
    const float* __restrict__ x, const float* __restrict__ e1w,
    const float* __restrict__ e2w, const int* __restrict__ e1p,
    const int* __restrict__ e2p, unsigned short* __restrict__ h,
    const int* __restrict__ wr, const int* __restrict__ wc,
    const float* __restrict__ wv, const int* __restrict__ bidx,
    const float* __restrict__ bv, float* __restrict__ Wd,
    float* __restrict__ bias) {
  __shared__ float xrow[F0v];
  __shared__ int   tsrc[E1v + E2v];
  __shared__ float twa[E1v + E2v];
  __shared__ float twb[E1v + E2v];
  const int tid = threadIdx.x;

  if (blockIdx.x >= BROWS) {
    int gid = (blockIdx.x - BROWS) * 256 + tid;
    if (gid < NNZv)
      atomicAdd(&Wd[(size_t)wr[gid] * F2v + wc[gid]], wv[gid]);
    if (gid < NBv)
      atomicAdd(&bias[bidx[gid]], bv[gid]);
    return;
  }

  const int b = blockIdx.x;
  const float* xr = x + (size_t)b * F0v;
  unsigned short* hr = h + (size_t)b * F2v;

  {
    tsrc[tid] = e1p[tid]; twa[tid] = e1w[tid]; twb[tid] = 1.0f;
    int p2 = e2p[tid]; float w2 = e2w[tid];
    if (p2 < F0v) {
      tsrc[E1v + tid] = p2;  twa[E1v + tid] = w2;  twb[E1v + tid] = 1.0f;
    } else {
      int q = p2 - F0v;
      tsrc[E1v + tid] = e1p[q]; twa[E1v + tid] = e1w[q]; twb[E1v + tid] = w2;
    }
  }

  float4 v0 = ((const float4*)xr)[tid * 2];
  float4 v1 = ((const float4*)xr)[tid * 2 + 1];
  ((float4*)xrow)[tid * 2] = v0;
  ((float4*)xrow)[tid * 2 + 1] = v1;
  union { unsigned short us[8]; uint4 u4; } pk;
  pk.us[0] = f2bf(v0.x); pk.us[1] = f2bf(v0.y);
  pk.us[2] = f2bf(v0.z); pk.us[3] = f2bf(v0.w);
  pk.us[4] = f2bf(v1.x); pk.us[5] = f2bf(v1.y);
  pk.us[6] = f2bf(v1.z); pk.us[7] = f2bf(v1.w);
  ((uint4*)hr)[tid] = pk.u4;
  __syncthreads();

  int j0 = tid * 2;
  float a0 = fmaxf(fmaxf(xrow[tsrc[j0]] * twa[j0], 0.0f) * twb[j0], 0.0f);
  float a1 = fmaxf(fmaxf(xrow[tsrc[j0 + 1]] * twa[j0 + 1], 0.0f) * twb[j0 + 1], 0.0f);
  unsigned int packed = (unsigned int)f2bf(a0) | ((unsigned int)f2bf(a1) << 16);
  ((unsigned int*)(hr + F0v))[tid] = packed;
}

// ---------------------------------------------------------------------------
// Kernel 2: W f32 -> bf16 (8 elems/thread)
// ---------------------------------------------------------------------------
__global__ __launch_bounds__(256) void convert_kernel(
    const float* __restrict__ Wd, unsigned short* __restrict__ Wb) {
  int gid = blockIdx.x * 256 + threadIdx.x;
  const float4* src = (const float4*)Wd;
  float4 a = src[gid * 2];
  float4 b = src[gid * 2 + 1];
  union { unsigned short us[8]; uint4 u4; } pk;
  pk.us[0] = f2bf(a.x); pk.us[1] = f2bf(a.y);
  pk.us[2] = f2bf(a.z); pk.us[3] = f2bf(a.w);
  pk.us[4] = f2bf(b.x); pk.us[5] = f2bf(b.y);
  pk.us[6] = f2bf(b.z); pk.us[7] = f2bf(b.w);
  ((uint4*)Wb)[gid] = pk.u4;
}

// ---------------------------------------------------------------------------
// Kernel 3: C = h @ W^T + bias.  BM=256 x BN=128, BK=64, 512 thr (8 waves,
// 4M x 2N), wave-tile 64x64, triple-buffered LDS (3 x 48 KB).
//
// ROUND-3 FIX: the 8-phase lockstep serialized the LDS pipe (1536 cyc/K-tile)
// against the MFMA pipe (1241 cyc/K-tile) -> 46 µs matched the serial model.
// Now ONE vmcnt + ONE barrier per K-tile; inside the tile body the 16
// ds_read_b128 and 32 MFMAs are plain dataflow: the compiler's fine-grained
// lgkmcnt lets the LDS pipe stream while the MFMA pipe consumes earlier
// fragments, and waves drift out of lockstep (setprio arbitrates).
// Counted vmcnt(6): tile t+1's 6 loads stay in flight across the barrier —
// never drained except at the final tile.  Race-freedom (triple buffer):
// stage t+2 -> buffer of t-1, whose ds_reads all retired before this
// barrier (they fed MFMAs in iter t-1); vmcnt(6)+barrier => tile t fully
// landed for every wave's portion before any wave reads it.
// ---------------------------------------------------------------------------
#define BM 256
#define BN 128
#define BK 64
#define NT 40                 // K-tiles = F2v / BK
#define BUFE 24576            // elems per buffer: (256+128)*64
#define AOFF 16384            // B-matrix offset within buffer (elems)

#define STA(t, buf, u) \
  async_ld16(gA + (size_t)(u) * 64 * F2v + (t) * BK, \
             &lds[(buf) * BUFE + (u) * 4096 + tid * 8])
#define STB(t, buf, u) \
  async_ld16(gB + (size_t)(u) * 64 * F2v + (t) * BK, \
             &lds[(buf) * BUFE + AOFF + (u) * 4096 + tid * 8])

#define LDA(buf, mi, kk) \
  (*(const bf16x8*)&lds[(buf) * BUFE + rowA[mi] + segq[kk]])
#define LDB(buf, ni, kk) \
  (*(const bf16x8*)&lds[(buf) * BUFE + AOFF + rowB[ni] + segq[kk]])

#define MF(mi, ni) \
  acc[mi][ni] = __builtin_amdgcn_mfma_f32_16x16x32_bf16(af[mi][0], bfr[ni][0], acc[mi][ni], 0, 0, 0); \
  acc[mi][ni] = __builtin_amdgcn_mfma_f32_16x16x32_bf16(af[mi][1], bfr[ni][1], acc[mi][ni], 0, 0, 0);

#define BAR() __builtin_amdgcn_s_barrier()
#define PRIO1() __builtin_amdgcn_s_setprio(1)
#define PRIO0() __builtin_amdgcn_s_setprio(0)

__global__ __launch_bounds__(512, 2) void gemm_bt_kernel(
    const unsigned short* __restrict__ A,
    const unsigned short* __restrict__ Bw,
    const float* __restrict__ bias,
    float* __restrict__ C) {
  extern __shared__ unsigned short lds[];
  const int tid  = threadIdx.x;
  const int wave = tid >> 6;      // 0..7
  const int lane = tid & 63;
  const int wm = wave >> 1;       // 0..3 (64-row quarter of M)
  const int wn = wave & 1;        // 0..1 (64-col half of N)
  const int quad = lane >> 4;     // 0..3
  const int r16 = lane & 15;
  const int r7 = r16 & 7;

  // XCD-aware decode (round-2 fix, verified: FETCH 166->41 MB): 256 blocks,
  // id%8 = XCD. XCD k owns M-tiles [4k,4k+4) x all 8 N-tiles (32 CUs).
  const int id  = blockIdx.y * 8 + blockIdx.x;
  const int xcd = id & 7;
  const int j   = id >> 3;                  // 0..31 within XCD
  const int m0 = (xcd * 4 + (j & 3)) * BM;  // M-tile 0..31
  const int n0 = (j >> 2) * BN;             // N-tile 0..7

  // Staging: call = 64-row unit (8 KB = 512 thr x 16 B). Thread tid: row
  // tid/8 within unit, stored seg tid%8, sourcing global seg (tid%8)^(row&7)
  // (pre-swizzled source, linear LDS dest = wave-uniform base + lane*16).
  const int srow = tid >> 3;                       // 0..63
  const int sseg8 = ((tid & 7) ^ (srow & 7)) * 8;
  const unsigned short* gA = A  + (size_t)(m0 + srow) * F2v + sseg8;
  const unsigned short* gB = Bw + (size_t)(n0 + srow) * F2v + sseg8;

  // Frag-read invariants; read seg = (kk*4+quad)^(row&7), row&7 == r16&7.
  int rowA[4], rowB[4], segq[2];
#pragma unroll
  for (int i = 0; i < 4; ++i) {
    rowA[i] = (wm * 64 + i * 16 + r16) * 64;
    rowB[i] = (wn * 64 + i * 16 + r16) * 64;
  }
  segq[0] = ((quad) ^ r7) * 8;
  segq[1] = ((4 + quad) ^ r7) * 8;

  floatx4 acc[4][4];
  floatx4 zz = {0.f, 0.f, 0.f, 0.f};
#pragma unroll
  for (int i = 0; i < 4; ++i)
#pragma unroll
    for (int j2 = 0; j2 < 4; ++j2) acc[i][j2] = zz;

  bf16x8 af[4][2], bfr[4][2];

  // Prologue: stage tiles 0 -> buf0, 1 -> buf1 (6 calls each)
#pragma unroll
  for (int u = 0; u < 4; ++u) STA(0, 0, u);
  STB(0, 0, 0); STB(0, 0, 1);
#pragma unroll
  for (int u = 0; u < 4; ++u) STA(1, 1, u);
  STB(1, 1, 0); STB(1, 1, 1);

  int c0 = 0, c1 = 1, c2 = 2;   // buffers of tiles t, t+1, t+2
  for (int t = 0; t < NT; ++t) {
    // Outstanding here: tile t (6) + tile t+1 (6). Counted wait: tile t
    // landed, t+1 stays in flight. Final tile: full drain (nothing behind).
    if (t < NT - 1) asm volatile("s_waitcnt vmcnt(6)" ::: "memory");
    else            asm volatile("s_waitcnt vmcnt(0)" ::: "memory");
    BAR();   // every wave's portion of tile t is in LDS; t-1 reads all retired

    if (t + 2 < NT) {   // stage t+2 into c2 (= buffer of consumed tile t-1)
#pragma unroll
      for (int u = 0; u < 4; ++u) STA(t + 2, c2, u);
      STB(t + 2, c2, 0); STB(t + 2, c2, 1);
    }

    // Tile body: 16 ds_read_b128 + 32 MFMA, no barriers. Compiler inserts
    // counted lgkmcnt per dataflow -> LDS pipe streams under the MFMA pipe.
    af[0][0] = LDA(c0, 0, 0); af[0][1] = LDA(c0, 0, 1);
    bfr[0][0] = LDB(c0, 0, 0); bfr[0][1] = LDB(c0, 0, 1);
    af[1][0] = LDA(c0, 1, 0); af[1][1] = LDA(c0, 1, 1);
    bfr[1][0] = LDB(c0, 1, 0); bfr[1][1] = LDB(c0, 1, 1);
    af[2][0] = LDA(c0, 2, 0); af[2][1] = LDA(c0, 2, 1);
    bfr[2][0] = LDB(c0, 2, 0); bfr[2][1] = LDB(c0, 2, 1);
    af[3][0] = LDA(c0, 3, 0); af[3][1] = LDA(c0, 3, 1);
    bfr[3][0] = LDB(c0, 3, 0); bfr[3][1] = LDB(c0, 3, 1);

    PRIO1();
    MF(0, 0) MF(0, 1) MF(1, 0) MF(1, 1)
    MF(0, 2) MF(0, 3) MF(1, 2) MF(1, 3)
    MF(2, 0) MF(2, 1) MF(3, 0) MF(3, 1)
    MF(2, 2) MF(2, 3) MF(3, 2) MF(3, 3)
    PRIO0();

    int tmp = c0; c0 = c1; c1 = c2; c2 = tmp;
  }

  // Epilogue: C/D layout col = lane&15, row = quad*4 + reg (m89/m91 verified)
#pragma unroll
  for (int ni = 0; ni < 4; ++ni) {
    int col = n0 + wn * 64 + ni * 16 + r16;
    float bc = bias[col];
#pragma unroll
    for (int mi = 0; mi < 4; ++mi) {
      int row = m0 + wm * 64 + mi * 16 + quad * 4;
#pragma unroll
      for (int rg = 0; rg < 4; ++rg)
        C[(size_t)(row + rg) * ODIM + col] = acc[mi][ni][rg] + bc;
    }
  }
}

// ---------------------------------------------------------------------------
extern "C" void kernel_launch(void* const* d_in, const int* in_sizes, int n_in,
                              void* d_out, int out_size, void* d_ws, size_t ws_size,
                              hipStream_t stream) {
  const float* x    = (const float*)d_in[0];
  const float* e1w  = (const float*)d_in[1];
  const float* e2w  = (const float*)d_in[2];
  const float* wv   = (const float*)d_in[3];
  const float* bv   = (const float*)d_in[4];
  const int*   e1p  = (const int*)d_in[5];
  const int*   e2p  = (const int*)d_in[6];
  const int*   wr   = (const int*)d_in[7];
  const int*   wc   = (const int*)d_in[8];
  const int*   bidx = (const int*)d_in[9];
  float* out = (float*)d_out;

  // Workspace carve (total ~57.7 MB)
  char* ws = (char*)d_ws;
  const size_t h_bytes  = (size_t)BROWS * F2v * 2;        // 41,943,040
  const size_t wd_bytes = (size_t)ODIM * F2v * 4;         // 10,485,760
  const size_t b_bytes  = (size_t)ODIM * 4;               // 4,096
  unsigned short* h   = (unsigned short*)ws;
  float* Wd           = (float*)(ws + h_bytes);
  float* bias         = (float*)(ws + h_bytes + wd_bytes);
  unsigned short* Wb  = (unsigned short*)(ws + h_bytes + wd_bytes + b_bytes);

  hipMemsetAsync(Wd, 0, wd_bytes + b_bytes, stream);
  fused_pre_kernel<<<BROWS + NNZv / 256, 256, 0, stream>>>(
      x, e1w, e2w, e1p, e2p, h, wr, wc, wv, bidx, bv, Wd, bias);
  convert_kernel<<<(ODIM * F2v / 8) / 256, 256, 0, stream>>>(Wd, Wb);

  // 144 KB dynamic LDS (3 x 48 KB triple buffer) — raise the cap, then launch
  hipFuncSetAttribute(reinterpret_cast<const void*>(gemm_bt_kernel),
                      hipFuncAttributeMaxDynamicSharedMemorySize, 3 * BUFE * 2);
  gemm_bt_kernel<<<dim3(ODIM / BN, BROWS / BM), 512, 3 * BUFE * 2, stream>>>(
      h, Wb, bias, out);
}

// Round 5
// 178.268 us; speedup vs baseline: 1.0105x; 1.0105x over previous
//
#include <hip/hip_runtime.h>
#include <hip/hip_bf16.h>
#include <cstdint>
#include <cstddef>

// Problem constants (from reference)
#define F0v   2048
#define F1v   2304
#define F2v   2560
#define E1v   256
#define E2v   256
#define BROWS 8192
#define ODIM  1024
#define NNZv  262144
#define NBv   1024

typedef __bf16 bf16x8 __attribute__((ext_vector_type(8)));
typedef float floatx4 __attribute__((ext_vector_type(4)));

__device__ __forceinline__ unsigned short f2bf(float f) {
  unsigned int u = __float_as_uint(f);
  u += 0x7FFFu + ((u >> 16) & 1u);   // round-to-nearest-even
  return (unsigned short)(u >> 16);
}

__device__ __forceinline__ void async_ld16(const void* g, void* l) {
  __builtin_amdgcn_global_load_lds(
      (const __attribute__((address_space(1))) unsigned int*)g,
      (__attribute__((address_space(3))) unsigned int*)l, 16, 0, 0);
}

// ---------------------------------------------------------------------------
// Kernel 1 (fused): proven round-0 version. Blocks [0,8192) build h rows
// (LDS-staged row -> gathers are LDS-hits; one barrier); blocks [8192,9216)
// do the COO scatter-add.
// ---------------------------------------------------------------------------
__global__ __launch_bounds__(256) void fused_pre_kernel(
    const float* __restrict__ x, const float* __restrict__ e1w,
    const float* __restrict__ e2w, const int* __restrict__ e1p,
    const int* __restrict__ e2p, unsigned short* __restrict__ h,
    const int* __restrict__ wr, const int* __restrict__ wc,
    const float* __restrict__ wv, const int* __restrict__ bidx,
    const float* __restrict__ bv, float* __restrict__ Wd,
    float* __restrict__ bias) {
  __shared__ float xrow[F0v];
  __shared__ int   tsrc[E1v + E2v];
  __shared__ float twa[E1v + E2v];
  __shared__ float twb[E1v + E2v];
  const int tid = threadIdx.x;

  if (blockIdx.x >= BROWS) {
    int gid = (blockIdx.x - BROWS) * 256 + tid;
    if (gid < NNZv)
      atomicAdd(&Wd[(size_t)wr[gid] * F2v + wc[gid]], wv[gid]);
    if (gid < NBv)
      atomicAdd(&bias[bidx[gid]], bv[gid]);
    return;
  }

  const int b = blockIdx.x;
  const float* xr = x + (size_t)b * F0v;
  unsigned short* hr = h + (size_t)b * F2v;

  {
    tsrc[tid] = e1p[tid]; twa[tid] = e1w[tid]; twb[tid] = 1.0f;
    int p2 = e2p[tid]; float w2 = e2w[tid];
    if (p2 < F0v) {
      tsrc[E1v + tid] = p2;  twa[E1v + tid] = w2;  twb[E1v + tid] = 1.0f;
    } else {
      int q = p2 - F0v;
      tsrc[E1v + tid] = e1p[q]; twa[E1v + tid] = e1w[q]; twb[E1v + tid] = w2;
    }
  }

  float4 v0 = ((const float4*)xr)[tid * 2];
  float4 v1 = ((const float4*)xr)[tid * 2 + 1];
  ((float4*)xrow)[tid * 2] = v0;
  ((float4*)xrow)[tid * 2 + 1] = v1;
  union { unsigned short us[8]; uint4 u4; } pk;
  pk.us[0] = f2bf(v0.x); pk.us[1] = f2bf(v0.y);
  pk.us[2] = f2bf(v0.z); pk.us[3] = f2bf(v0.w);
  pk.us[4] = f2bf(v1.x); pk.us[5] = f2bf(v1.y);
  pk.us[6] = f2bf(v1.z); pk.us[7] = f2bf(v1.w);
  ((uint4*)hr)[tid] = pk.u4;
  __syncthreads();

  int j0 = tid * 2;
  float a0 = fmaxf(fmaxf(xrow[tsrc[j0]] * twa[j0], 0.0f) * twb[j0], 0.0f);
  float a1 = fmaxf(fmaxf(xrow[tsrc[j0 + 1]] * twa[j0 + 1], 0.0f) * twb[j0 + 1], 0.0f);
  unsigned int packed = (unsigned int)f2bf(a0) | ((unsigned int)f2bf(a1) << 16);
  ((unsigned int*)(hr + F0v))[tid] = packed;
}

// ---------------------------------------------------------------------------
// Kernel 2: W f32 -> bf16 (8 elems/thread)
// ---------------------------------------------------------------------------
__global__ __launch_bounds__(256) void convert_kernel(
    const float* __restrict__ Wd, unsigned short* __restrict__ Wb) {
  int gid = blockIdx.x * 256 + threadIdx.x;
  const float4* src = (const float4*)Wd;
  float4 a = src[gid * 2];
  float4 b = src[gid * 2 + 1];
  union { unsigned short us[8]; uint4 u4; } pk;
  pk.us[0] = f2bf(a.x); pk.us[1] = f2bf(a.y);
  pk.us[2] = f2bf(a.z); pk.us[3] = f2bf(a.w);
  pk.us[4] = f2bf(b.x); pk.us[5] = f2bf(b.y);
  pk.us[6] = f2bf(b.z); pk.us[7] = f2bf(b.w);
  ((uint4*)Wb)[gid] = pk.u4;
}

// ---------------------------------------------------------------------------
// Kernel 3: C = h @ W^T + bias.  BM=256 x BN=128, BK=64, 512 thr (8 waves,
// 4M x 2N, wave-tile 64x64), triple-buffered LDS (3 x 48 KB), counted
// vmcnt(6), XCD-aware decode (FETCH 41 MB verified).
//
// ROUND-4 FIX: cross-window FRAGMENT pipelining. Rounds 3-4 measured
// ~2846 cyc/K-tile = LDS-read burst (1536) + MFMA burst (1242) SERIALIZED,
// because each wave's MFMAs depended on its just-issued ds_reads (in-order
// issue + lgkm wait). Now window w ds_reads tile w's fragments into reg set
// S[w&1] and MFMAs tile w-1 from S[(w-1)&1]: no wait between the read burst
// and the MFMA burst -> LDS pipe and MFMA pipe overlap. lgkmcnt(0) before
// each barrier closes the buffer-reuse race (free: reads had a full MFMA
// phase to land). sched_barrier(0) keeps reads above the MFMA cluster.
// ---------------------------------------------------------------------------
#define BM 256
#define BN 128
#define BK 64
#define NT 40                 // K-tiles = F2v / BK
#define BUFE 24576            // elems per buffer: (256+128)*64
#define AOFF 16384            // B-matrix offset within buffer (elems)

#define STA(t, buf, u) \
  async_ld16(gA + (size_t)(u) * 64 * F2v + (t) * BK, \
             &lds[(buf) * BUFE + (u) * 4096 + tid * 8])
#define STB(t, buf, u) \
  async_ld16(gB + (size_t)(u) * 64 * F2v + (t) * BK, \
             &lds[(buf) * BUFE + AOFF + (u) * 4096 + tid * 8])
#define STAGE(t, buf) \
  { STA(t, buf, 0); STA(t, buf, 1); STA(t, buf, 2); STA(t, buf, 3); \
    STB(t, buf, 0); STB(t, buf, 1); }

#define LDA(buf, mi, kk) \
  (*(const bf16x8*)&lds[(buf) * BUFE + rowA[mi] + segq[kk]])
#define LDB(buf, ni, kk) \
  (*(const bf16x8*)&lds[(buf) * BUFE + AOFF + rowB[ni] + segq[kk]])

#define RD_ALL(SA, SB, cbuf) \
  SA[0][0]=LDA(cbuf,0,0); SA[0][1]=LDA(cbuf,0,1); \
  SA[1][0]=LDA(cbuf,1,0); SA[1][1]=LDA(cbuf,1,1); \
  SA[2][0]=LDA(cbuf,2,0); SA[2][1]=LDA(cbuf,2,1); \
  SA[3][0]=LDA(cbuf,3,0); SA[3][1]=LDA(cbuf,3,1); \
  SB[0][0]=LDB(cbuf,0,0); SB[0][1]=LDB(cbuf,0,1); \
  SB[1][0]=LDB(cbuf,1,0); SB[1][1]=LDB(cbuf,1,1); \
  SB[2][0]=LDB(cbuf,2,0); SB[2][1]=LDB(cbuf,2,1); \
  SB[3][0]=LDB(cbuf,3,0); SB[3][1]=LDB(cbuf,3,1);

#define MM(SA, SB, mi, ni, kk) \
  acc[mi][ni] = __builtin_amdgcn_mfma_f32_16x16x32_bf16(SA[mi][kk], SB[ni][kk], acc[mi][ni], 0, 0, 0);

// kk0 pass (16 independent cells) then kk1 pass — no adjacent dependent pairs
#define MF_ALL(SA, SB) \
  PRIO1(); \
  MM(SA,SB,0,0,0) MM(SA,SB,0,1,0) MM(SA,SB,1,0,0) MM(SA,SB,1,1,0) \
  MM(SA,SB,0,2,0) MM(SA,SB,0,3,0) MM(SA,SB,1,2,0) MM(SA,SB,1,3,0) \
  MM(SA,SB,2,0,0) MM(SA,SB,2,1,0) MM(SA,SB,3,0,0) MM(SA,SB,3,1,0) \
  MM(SA,SB,2,2,0) MM(SA,SB,2,3,0) MM(SA,SB,3,2,0) MM(SA,SB,3,3,0) \
  MM(SA,SB,0,0,1) MM(SA,SB,0,1,1) MM(SA,SB,1,0,1) MM(SA,SB,1,1,1) \
  MM(SA,SB,0,2,1) MM(SA,SB,0,3,1) MM(SA,SB,1,2,1) MM(SA,SB,1,3,1) \
  MM(SA,SB,2,0,1) MM(SA,SB,2,1,1) MM(SA,SB,3,0,1) MM(SA,SB,3,1,1) \
  MM(SA,SB,2,2,1) MM(SA,SB,2,3,1) MM(SA,SB,3,2,1) MM(SA,SB,3,3,1) \
  PRIO0();

#define BAR() __builtin_amdgcn_s_barrier()
#define PRIO1() __builtin_amdgcn_s_setprio(1)
#define PRIO0() __builtin_amdgcn_s_setprio(0)
#define SCHED0() __builtin_amdgcn_sched_barrier(0)
#define ROT() { int tmp = c0; c0 = c1; c1 = c2; c2 = tmp; }

__global__ __launch_bounds__(512, 2) void gemm_bt_kernel(
    const unsigned short* __restrict__ A,
    const unsigned short* __restrict__ Bw,
    const float* __restrict__ bias,
    float* __restrict__ C) {
  extern __shared__ unsigned short lds[];
  const int tid  = threadIdx.x;
  const int wave = tid >> 6;      // 0..7
  const int lane = tid & 63;
  const int wm = wave >> 1;       // 0..3 (64-row quarter of M)
  const int wn = wave & 1;        // 0..1 (64-col half of N)
  const int quad = lane >> 4;     // 0..3
  const int r16 = lane & 15;
  const int r7 = r16 & 7;

  // XCD-aware decode: 256 blocks, id%8 = XCD. XCD k owns M-tiles [4k,4k+4).
  const int id  = blockIdx.y * 8 + blockIdx.x;
  const int xcd = id & 7;
  const int j   = id >> 3;
  const int m0 = (xcd * 4 + (j & 3)) * BM;
  const int n0 = (j >> 2) * BN;

  // Staging: thread tid stages row tid/8, stored seg tid%8, sourcing global
  // seg (tid%8)^(row&7) — pre-swizzled source, linear LDS dest.
  const int srow = tid >> 3;
  const int sseg8 = ((tid & 7) ^ (srow & 7)) * 8;
  const unsigned short* gA = A  + (size_t)(m0 + srow) * F2v + sseg8;
  const unsigned short* gB = Bw + (size_t)(n0 + srow) * F2v + sseg8;

  // Frag-read invariants; read seg = (kk*4+quad)^(row&7), row&7 == r16&7.
  int rowA[4], rowB[4], segq[2];
#pragma unroll
  for (int i = 0; i < 4; ++i) {
    rowA[i] = (wm * 64 + i * 16 + r16) * 64;
    rowB[i] = (wn * 64 + i * 16 + r16) * 64;
  }
  segq[0] = ((quad) ^ r7) * 8;
  segq[1] = ((4 + quad) ^ r7) * 8;

  floatx4 acc[4][4];
  floatx4 zz = {0.f, 0.f, 0.f, 0.f};
#pragma unroll
  for (int i = 0; i < 4; ++i)
#pragma unroll
    for (int j2 = 0; j2 < 4; ++j2) acc[i][j2] = zz;

  bf16x8 afX[4][2], bfX[4][2], afY[4][2], bfY[4][2];

  // Prologue: stage tiles 0 -> buf0, 1 -> buf1
  STAGE(0, 0)
  STAGE(1, 1)
  int c0 = 0, c1 = 1, c2 = 2;

  // ---- window 0: read tile 0 -> X (no MFMA yet)
  asm volatile("s_waitcnt vmcnt(6)" ::: "memory");
  BAR();
  STAGE(2, c2)
  RD_ALL(afX, bfX, c0)
  asm volatile("s_waitcnt lgkmcnt(0)" ::: "memory");
  ROT()

#pragma unroll 1
  for (int wp = 0; wp < 20; ++wp) {
    // ---- odd window w = 2wp+1: read tile w -> Y, MFMA tile 2wp from X
    if (wp < 19) asm volatile("s_waitcnt vmcnt(6)" ::: "memory");
    else         asm volatile("s_waitcnt vmcnt(0)" ::: "memory");
    BAR();
    if (2 * wp + 3 < NT) STAGE(2 * wp + 3, c2)
    RD_ALL(afY, bfY, c0)
    SCHED0();
    MF_ALL(afX, bfX)
    asm volatile("s_waitcnt lgkmcnt(0)" ::: "memory");
    ROT()

    // ---- even window w = 2wp+2: read tile w -> X, MFMA tile 2wp+1 from Y
    if (wp < 19) {
      asm volatile("s_waitcnt vmcnt(6)" ::: "memory");
      BAR();
      if (2 * wp + 4 < NT) STAGE(2 * wp + 4, c2)
      RD_ALL(afX, bfX, c0)
      SCHED0();
      MF_ALL(afY, bfY)
      asm volatile("s_waitcnt lgkmcnt(0)" ::: "memory");
      ROT()
    }
  }
  // ---- final: MFMA tile 39 from Y
  MF_ALL(afY, bfY)

  // Epilogue: C/D layout col = lane&15, row = quad*4 + reg (m89/m91 verified)
#pragma unroll
  for (int ni = 0; ni < 4; ++ni) {
    int col = n0 + wn * 64 + ni * 16 + r16;
    float bc = bias[col];
#pragma unroll
    for (int mi = 0; mi < 4; ++mi) {
      int row = m0 + wm * 64 + mi * 16 + quad * 4;
#pragma unroll
      for (int rg = 0; rg < 4; ++rg)
        C[(size_t)(row + rg) * ODIM + col] = acc[mi][ni][rg] + bc;
    }
  }
}

// ---------------------------------------------------------------------------
extern "C" void kernel_launch(void* const* d_in, const int* in_sizes, int n_in,
                              void* d_out, int out_size, void* d_ws, size_t ws_size,
                              hipStream_t stream) {
  const float* x    = (const float*)d_in[0];
  const float* e1w  = (const float*)d_in[1];
  const float* e2w  = (const float*)d_in[2];
  const float* wv   = (const float*)d_in[3];
  const float* bv   = (const float*)d_in[4];
  const int*   e1p  = (const int*)d_in[5];
  const int*   e2p  = (const int*)d_in[6];
  const int*   wr   = (const int*)d_in[7];
  const int*   wc   = (const int*)d_in[8];
  const int*   bidx = (const int*)d_in[9];
  float* out = (float*)d_out;

  // Workspace carve (total ~57.7 MB)
  char* ws = (char*)d_ws;
  const size_t h_bytes  = (size_t)BROWS * F2v * 2;        // 41,943,040
  const size_t wd_bytes = (size_t)ODIM * F2v * 4;         // 10,485,760
  const size_t b_bytes  = (size_t)ODIM * 4;               // 4,096
  unsigned short* h   = (unsigned short*)ws;
  float* Wd           = (float*)(ws + h_bytes);
  float* bias         = (float*)(ws + h_bytes + wd_bytes);
  unsigned short* Wb  = (unsigned short*)(ws + h_bytes + wd_bytes + b_bytes);

  hipMemsetAsync(Wd, 0, wd_bytes + b_bytes, stream);
  fused_pre_kernel<<<BROWS + NNZv / 256, 256, 0, stream>>>(
      x, e1w, e2w, e1p, e2p, h, wr, wc, wv, bidx, bv, Wd, bias);
  convert_kernel<<<(ODIM * F2v / 8) / 256, 256, 0, stream>>>(Wd, Wb);

  // 144 KB dynamic LDS (3 x 48 KB triple buffer)
  hipFuncSetAttribute(reinterpret_cast<const void*>(gemm_bt_kernel),
                      hipFuncAttributeMaxDynamicSharedMemorySize, 3 * BUFE * 2);
  gemm_bt_kernel<<<dim3(ODIM / BN, BROWS / BM), 512, 3 * BUFE * 2, stream>>>(
      h, Wb, bias, out);
}